// Round 8
// baseline (38.184 us; speedup 1.0000x reference)
//
#include <hip/hip_runtime.h>
#include <hip/hip_bf16.h>

// FFM: out[b] = x_b . w_lin + b_lin + sum_{i<j} x_i W_ij x_j
// W_ij = dot(v[i, f_j, :], v[j, f_i, :])  (symmetric)
// M = 0.5*(Wu + Wu^T), zero diag, bf16, packed in MFMA B-fragment order.
// out = x . (M x + w) + b via 16x16x32 bf16 MFMA.
// R7 = R6 + counted-barrier: __syncthreads drains vmcnt(0) (kills prefetch);
//     replaced with "s_waitcnt lgkmcnt(0); s_barrier" so the 2-tile-ahead
//     x prefetch stays in flight across barriers (T4). Full unroll, two
//     statically-named prefetch pairs.

#define FK 256   // F*K = 32*8

typedef __attribute__((ext_vector_type(8))) short bf16x8;
typedef __attribute__((ext_vector_type(4))) float f32x4v;

__device__ __forceinline__ unsigned short f2bf(float x) {
    return __builtin_bit_cast(unsigned short, __float2bfloat16(x));
}
__device__ __forceinline__ float bf2f(unsigned short h) {
    return __builtin_bit_cast(float, (unsigned int)h << 16);
}

template<int CTRL>
__device__ __forceinline__ float dppadd(float v) {
    int t = __builtin_amdgcn_update_dpp(0, __builtin_bit_cast(int, v),
                                        CTRL, 0xf, 0xf, true);
    return v + __builtin_bit_cast(float, t);
}

// Barrier that does NOT drain vmcnt: LDS-visibility only.
__device__ __forceinline__ void block_sync_novm() {
    asm volatile("s_waitcnt lgkmcnt(0)\n\ts_barrier" ::: "memory");
}

// ---------------- Kernel 1: build packed M (bf16, B-fragment order) --------
// Frag f = (s*16+ct)*64 + l holds M[k][c] for i8=0..7:
//   k = s*32 + ((l>>4)&3)*8 + i8,  c = ct*16 + (l&15)
// One thread produces one uint (2 elems): u = f*4 + j, i8 = {2j, 2j+1}.
__global__ __launch_bounds__(128) void k_build_m(
    const float* __restrict__ v, const int* __restrict__ fidx,
    unsigned int* __restrict__ mp)
{
    __shared__ int fsh[256];
    int tid = threadIdx.x;
    fsh[tid] = fidx[tid];
    fsh[tid + 128] = fidx[tid + 128];
    __syncthreads();

    int u = blockIdx.x * 128 + tid;           // 32768 threads
    int f  = u >> 2;
    int l  = f & 63;
    int ct = (f >> 6) & 15;
    int s  = f >> 10;                          // 0..7
    int c  = ct * 16 + (l & 15);
    int i80 = (u & 3) * 2;
    int k0 = s * 32 + ((l >> 4) & 3) * 8 + i80;
    int fc = fsh[c];
    unsigned short hh[2];
#pragma unroll
    for (int i = 0; i < 2; ++i) {
        int k = k0 + i;
        float acc = 0.f;
        if (k != c) {
            int fk = fsh[k];
            const float* va = v + k * FK + fc * 8;   // v[k, f_c, :]
            const float* vb = v + c * FK + fk * 8;   // v[c, f_k, :]
#pragma unroll
            for (int j = 0; j < 8; ++j) acc += va[j] * vb[j];
            acc *= 0.5f;
        }
        hh[i] = f2bf(acc);
    }
    mp[u] = (unsigned int)hh[0] | ((unsigned int)hh[1] << 16);
}

// ---------------- Kernel 2: main --------------------------------------------
// 512 blocks x 512 threads (8 waves), 128 rows/block, 8 tiles x 16 rows.
// Wave w owns cols [w*32, w*32+32); its B-fragments live in registers.
// x tile: 16 rows x 256 cols bf16, row stride 512 B, 16B chunks XOR-swizzled
// by ((row&7)<<4).

struct SmemT {
    unsigned short xs[2][4096];     // 2 x 8 KB
    float part[2][8][16];           // double-buffered partials
};

__device__ __forceinline__ void stage_write(unsigned short* buf, float4 val,
                                            int row, int chunk) {
    unsigned long long h0 = f2bf(val.x), h1 = f2bf(val.y),
                       h2 = f2bf(val.z), h3 = f2bf(val.w);
    unsigned long long pk = h0 | (h1 << 16) | (h2 << 32) | (h3 << 48);
    int byteoff = row * 512 + ((chunk * 8) ^ ((row & 7) << 4));
    *(unsigned long long*)((char*)buf + byteoff) = pk;
}

__global__ __launch_bounds__(512, 4) void k_main(
    const float* __restrict__ x, const float* __restrict__ w_lin,
    const float* __restrict__ b_lin, const uint4* __restrict__ mpack,
    float* __restrict__ out)
{
    __shared__ SmemT sm;

    const int tid = threadIdx.x;
    const int w   = tid >> 6;        // 0..7
    const int l   = tid & 63;
    const int l15 = l & 15;
    const int lg  = l >> 4;          // 0..3

    const long rowbase = (long)blockIdx.x * 128;   // 128 rows per block
    const float* xg = x + rowbase * 256;

    const int srow = w * 2 + (l >> 5);   // row in tile this lane stages
    const int sc0  = l & 31;             // first 16B chunk
    const int sc1  = sc0 + 32;           // second 16B chunk

    // ---- prologue issue order: tile0 (HBM) -> Brg (L2) -> tile1 -> tile2 ---
    float4 a0 = *(const float4*)(xg + srow * 256 + sc0 * 4);
    float4 b0 = *(const float4*)(xg + srow * 256 + sc1 * 4);

    bf16x8 Brg[8][2];
#pragma unroll
    for (int s = 0; s < 8; ++s)
#pragma unroll
        for (int ct = 0; ct < 2; ++ct)
            Brg[s][ct] = __builtin_bit_cast(bf16x8,
                mpack[(s * 16 + w * 2 + ct) * 64 + l]);

    float4 Pa1 = *(const float4*)(xg + (16 + srow) * 256 + sc0 * 4);
    float4 Pb1 = *(const float4*)(xg + (16 + srow) * 256 + sc1 * 4);
    float4 Pa0 = *(const float4*)(xg + (32 + srow) * 256 + sc0 * 4);
    float4 Pb0 = *(const float4*)(xg + (32 + srow) * 256 + sc1 * 4);

    const float w0 = w_lin[(w * 2 + 0) * 16 + l15];
    const float w1 = w_lin[(w * 2 + 1) * 16 + l15];
    const float bv = b_lin[0];

    stage_write(sm.xs[0], a0, srow, sc0);
    stage_write(sm.xs[0], b0, srow, sc1);
    block_sync_novm();

#pragma unroll
    for (int t = 0; t < 8; ++t) {
        const char* xsb = (const char*)sm.xs[t & 1];

        // ---- GEMM: acc = w + X_tile(16x256) @ M(:, wave cols) ----
        f32x4v acc0 = {w0, w0, w0, w0};
        f32x4v acc1 = {w1, w1, w1, w1};
#pragma unroll
        for (int s = 0; s < 8; ++s) {
            int aoff = l15 * 512 + ((s * 64 + lg * 16) ^ ((l15 & 7) << 4));
            bf16x8 af = *(const bf16x8*)(xsb + aoff);
            acc0 = __builtin_amdgcn_mfma_f32_16x16x32_bf16(af, Brg[s][0], acc0, 0, 0, 0);
            acc1 = __builtin_amdgcn_mfma_f32_16x16x32_bf16(af, Brg[s][1], acc1, 0, 0, 0);
        }

        // ---- dot: p[row] = sum_{cols of wave} x[row][col] * acc ----
        // C/D layout (m89): col = ct*16 + (lane&15), row = (lane>>4)*4 + reg
#pragma unroll
        for (int r = 0; r < 4; ++r) {
            int row = lg * 4 + r;
            int sw  = (row & 7) << 4;
            int c0  = (w * 2 + 0) * 16 + l15;
            int c1  = (w * 2 + 1) * 16 + l15;
            unsigned short h0 = *(const unsigned short*)(xsb + row * 512 + ((c0 * 2) ^ sw));
            unsigned short h1 = *(const unsigned short*)(xsb + row * 512 + ((c1 * 2) ^ sw));
            float pp = bf2f(h0) * acc0[r] + bf2f(h1) * acc1[r];
            pp = dppadd<0x121>(pp); pp = dppadd<0x122>(pp);
            pp = dppadd<0x124>(pp); pp = dppadd<0x128>(pp);
            if (l15 == 0) sm.part[t & 1][w][row] = pp;
        }

        // ---- stage tile t+1 (pair parity (t+1)&1); refill with tile t+3 ----
        if (t < 7) {
            unsigned short* nb = sm.xs[(t + 1) & 1];
            if (((t + 1) & 1) == 0) {
                stage_write(nb, Pa0, srow, sc0);
                stage_write(nb, Pb0, srow, sc1);
                if (t < 5) {
                    Pa0 = *(const float4*)(xg + ((t + 3) * 16 + srow) * 256 + sc0 * 4);
                    Pb0 = *(const float4*)(xg + ((t + 3) * 16 + srow) * 256 + sc1 * 4);
                }
            } else {
                stage_write(nb, Pa1, srow, sc0);
                stage_write(nb, Pb1, srow, sc1);
                if (t < 5) {
                    Pa1 = *(const float4*)(xg + ((t + 3) * 16 + srow) * 256 + sc0 * 4);
                    Pb1 = *(const float4*)(xg + ((t + 3) * 16 + srow) * 256 + sc1 * 4);
                }
            }
        }
        block_sync_novm();

        // ---- out write for tile t ----
        if (tid < 16) {
            const float (*pt)[16] = sm.part[t & 1];
            float y = pt[0][tid] + pt[1][tid] + pt[2][tid] + pt[3][tid] +
                      pt[4][tid] + pt[5][tid] + pt[6][tid] + pt[7][tid];
            out[rowbase + t * 16 + tid] = y + bv;
        }
    }
}

extern "C" void kernel_launch(void* const* d_in, const int* in_sizes, int n_in,
                              void* d_out, int out_size, void* d_ws, size_t ws_size,
                              hipStream_t stream) {
    const float* x     = (const float*)d_in[0];
    const float* w_lin = (const float*)d_in[1];
    const float* b_lin = (const float*)d_in[2];
    const float* v     = (const float*)d_in[3];
    const int*   fidx  = (const int*)d_in[4];
    float* out = (float*)d_out;
    void* mpack = d_ws;   // 128 KB

    k_build_m<<<256, 128, 0, stream>>>(v, fidx, (unsigned int*)mpack);
    k_main<<<512, 512, 0, stream>>>(x, w_lin, b_lin, (const uint4*)mpack, out);
}

// Round 9
// 23.517 us; speedup vs baseline: 1.6237x; 1.6237x over previous
//
#include <hip/hip_runtime.h>
#include <hip/hip_bf16.h>

// FFM: out[b] = x_b . w_lin + b_lin + sum_{i<j} x_i W_ij x_j
// W_ij = dot(v[i, f_j, :], v[j, f_i, :])  (symmetric)
// M = 0.5*(Wu + Wu^T), zero diag, bf16, packed in MFMA B-fragment order.
// out = x . (M x + w) + b via 16x16x32 bf16 MFMA.
// R8 = R6 structure + __launch_bounds__(512,2): R7 showed VGPR_Count=64
//     (launch_bounds 2nd arg acts CUDA-style blocks/CU here) -> Brg spilled
//     to scratch (WRITE_SIZE 16.7MB). (512,2) caps at 128 VGPR -> no spills,
//     2 blocks/CU. Rolling 2-ahead prefetch + lgkmcnt-only barrier.

#define FK 256   // F*K = 32*8

typedef __attribute__((ext_vector_type(8))) short bf16x8;
typedef __attribute__((ext_vector_type(4))) float f32x4v;

__device__ __forceinline__ unsigned short f2bf(float x) {
    return __builtin_bit_cast(unsigned short, __float2bfloat16(x));
}
__device__ __forceinline__ float bf2f(unsigned short h) {
    return __builtin_bit_cast(float, (unsigned int)h << 16);
}

template<int CTRL>
__device__ __forceinline__ float dppadd(float v) {
    int t = __builtin_amdgcn_update_dpp(0, __builtin_bit_cast(int, v),
                                        CTRL, 0xf, 0xf, true);
    return v + __builtin_bit_cast(float, t);
}

// Barrier that does NOT drain vmcnt: LDS-visibility only.
__device__ __forceinline__ void block_sync_novm() {
    asm volatile("s_waitcnt lgkmcnt(0)\n\ts_barrier" ::: "memory");
}

// ---------------- Kernel 1: build packed M (bf16, B-fragment order) --------
// Frag f = (s*16+ct)*64 + l holds M[k][c] for i8=0..7:
//   k = s*32 + ((l>>4)&3)*8 + i8,  c = ct*16 + (l&15)
// One thread produces one uint (2 elems): u = f*4 + j, i8 = {2j, 2j+1}.
__global__ __launch_bounds__(128) void k_build_m(
    const float* __restrict__ v, const int* __restrict__ fidx,
    unsigned int* __restrict__ mp)
{
    __shared__ int fsh[256];
    int tid = threadIdx.x;
    fsh[tid] = fidx[tid];
    fsh[tid + 128] = fidx[tid + 128];
    __syncthreads();

    int u = blockIdx.x * 128 + tid;           // 32768 threads
    int f  = u >> 2;
    int l  = f & 63;
    int ct = (f >> 6) & 15;
    int s  = f >> 10;                          // 0..7
    int c  = ct * 16 + (l & 15);
    int i80 = (u & 3) * 2;
    int k0 = s * 32 + ((l >> 4) & 3) * 8 + i80;
    int fc = fsh[c];
    unsigned short hh[2];
#pragma unroll
    for (int i = 0; i < 2; ++i) {
        int k = k0 + i;
        float acc = 0.f;
        if (k != c) {
            int fk = fsh[k];
            const float* va = v + k * FK + fc * 8;   // v[k, f_c, :]
            const float* vb = v + c * FK + fk * 8;   // v[c, f_k, :]
#pragma unroll
            for (int j = 0; j < 8; ++j) acc += va[j] * vb[j];
            acc *= 0.5f;
        }
        hh[i] = f2bf(acc);
    }
    mp[u] = (unsigned int)hh[0] | ((unsigned int)hh[1] << 16);
}

// ---------------- Kernel 2: main --------------------------------------------
// 512 blocks x 512 threads (8 waves), 128 rows/block, 8 tiles x 16 rows.
// Wave w owns cols [w*32, w*32+32); its B-fragments live in registers.
// x tile: 16 rows x 256 cols bf16, row stride 512 B, 16B chunks XOR-swizzled
// by ((row&7)<<4).

struct SmemT {
    unsigned short xs[2][4096];     // 2 x 8 KB
    float part[2][8][16];           // double-buffered partials
};

__device__ __forceinline__ void stage_write(unsigned short* buf, float4 val,
                                            int row, int chunk) {
    unsigned long long h0 = f2bf(val.x), h1 = f2bf(val.y),
                       h2 = f2bf(val.z), h3 = f2bf(val.w);
    unsigned long long pk = h0 | (h1 << 16) | (h2 << 32) | (h3 << 48);
    int byteoff = row * 512 + ((chunk * 8) ^ ((row & 7) << 4));
    *(unsigned long long*)((char*)buf + byteoff) = pk;
}

__global__ __launch_bounds__(512, 2) void k_main(
    const float* __restrict__ x, const float* __restrict__ w_lin,
    const float* __restrict__ b_lin, const uint4* __restrict__ mpack,
    float* __restrict__ out)
{
    __shared__ SmemT sm;

    const int tid = threadIdx.x;
    const int w   = tid >> 6;        // 0..7
    const int l   = tid & 63;
    const int l15 = l & 15;
    const int lg  = l >> 4;          // 0..3

    const long rowbase = (long)blockIdx.x * 128;   // 128 rows per block
    const float* xg = x + rowbase * 256;

    const int srow = w * 2 + (l >> 5);   // row in tile this lane stages
    const int sc0  = l & 31;             // first 16B chunk
    const int sc1  = sc0 + 32;           // second 16B chunk

    // ---- prologue: tile0 (HBM) -> Brg (L2) -> tile1 prefetch ----
    float4 a0 = *(const float4*)(xg + srow * 256 + sc0 * 4);
    float4 b0 = *(const float4*)(xg + srow * 256 + sc1 * 4);

    bf16x8 Brg[8][2];
#pragma unroll
    for (int s = 0; s < 8; ++s)
#pragma unroll
        for (int ct = 0; ct < 2; ++ct)
            Brg[s][ct] = __builtin_bit_cast(bf16x8,
                mpack[(s * 16 + w * 2 + ct) * 64 + l]);

    const float w0 = w_lin[(w * 2 + 0) * 16 + l15];
    const float w1 = w_lin[(w * 2 + 1) * 16 + l15];
    const float bv = b_lin[0];

    stage_write(sm.xs[0], a0, srow, sc0);
    stage_write(sm.xs[0], b0, srow, sc1);
    float4 pa = *(const float4*)(xg + (16 + srow) * 256 + sc0 * 4);
    float4 pb = *(const float4*)(xg + (16 + srow) * 256 + sc1 * 4);
    block_sync_novm();

    for (int t = 0; t < 8; ++t) {
        const char* xsb = (const char*)sm.xs[t & 1];

        // ---- GEMM: acc = w + X_tile(16x256) @ M(:, wave cols) ----
        f32x4v acc0 = {w0, w0, w0, w0};
        f32x4v acc1 = {w1, w1, w1, w1};
#pragma unroll
        for (int s = 0; s < 8; ++s) {
            int aoff = l15 * 512 + ((s * 64 + lg * 16) ^ ((l15 & 7) << 4));
            bf16x8 af = *(const bf16x8*)(xsb + aoff);
            acc0 = __builtin_amdgcn_mfma_f32_16x16x32_bf16(af, Brg[s][0], acc0, 0, 0, 0);
            acc1 = __builtin_amdgcn_mfma_f32_16x16x32_bf16(af, Brg[s][1], acc1, 0, 0, 0);
        }

        // ---- dot: p[row] = sum_{cols of wave} x[row][col] * acc ----
        // C/D layout (m89): col = ct*16 + (lane&15), row = (lane>>4)*4 + reg
#pragma unroll
        for (int r = 0; r < 4; ++r) {
            int row = lg * 4 + r;
            int sw  = (row & 7) << 4;
            int c0  = (w * 2 + 0) * 16 + l15;
            int c1  = (w * 2 + 1) * 16 + l15;
            unsigned short h0 = *(const unsigned short*)(xsb + row * 512 + ((c0 * 2) ^ sw));
            unsigned short h1 = *(const unsigned short*)(xsb + row * 512 + ((c1 * 2) ^ sw));
            float pp = bf2f(h0) * acc0[r] + bf2f(h1) * acc1[r];
            pp = dppadd<0x121>(pp); pp = dppadd<0x122>(pp);
            pp = dppadd<0x124>(pp); pp = dppadd<0x128>(pp);
            if (l15 == 0) sm.part[t & 1][w][row] = pp;
        }

        // ---- stage tile t+1 into other buffer; prefetch tile t+2 ----
        if (t < 7) {
            unsigned short* nb = sm.xs[(t + 1) & 1];
            stage_write(nb, pa, srow, sc0);
            stage_write(nb, pb, srow, sc1);
        }
        if (t < 6) {
            pa = *(const float4*)(xg + ((t + 2) * 16 + srow) * 256 + sc0 * 4);
            pb = *(const float4*)(xg + ((t + 2) * 16 + srow) * 256 + sc1 * 4);
        }
        block_sync_novm();

        // ---- out write for tile t ----
        if (tid < 16) {
            const float (*pt)[16] = sm.part[t & 1];
            float y = pt[0][tid] + pt[1][tid] + pt[2][tid] + pt[3][tid] +
                      pt[4][tid] + pt[5][tid] + pt[6][tid] + pt[7][tid];
            out[rowbase + t * 16 + tid] = y + bv;
        }
    }
}

extern "C" void kernel_launch(void* const* d_in, const int* in_sizes, int n_in,
                              void* d_out, int out_size, void* d_ws, size_t ws_size,
                              hipStream_t stream) {
    const float* x     = (const float*)d_in[0];
    const float* w_lin = (const float*)d_in[1];
    const float* b_lin = (const float*)d_in[2];
    const float* v     = (const float*)d_in[3];
    const int*   fidx  = (const int*)d_in[4];
    float* out = (float*)d_out;
    void* mpack = d_ws;   // 128 KB

    k_build_m<<<256, 128, 0, stream>>>(v, fidx, (unsigned int*)mpack);
    k_main<<<512, 512, 0, stream>>>(x, w_lin, b_lin, (const uint4*)mpack, out);
}